// Round 2
// baseline (27402.060 us; speedup 1.0000x reference)
//
#include <hip/hip_runtime.h>
#include <hip/hip_bf16.h>

// LSTM2: B=1024, T=1024, H=64, 2-layer LSTM + linear head, fp32 internal state.
// Input/output dtype (fp32 vs bf16) detected AT RUNTIME from weight bit patterns
// (uniform, data-derived, identical every call -> graph-capture safe).
//
// Mapping: 512 blocks x 256 threads; block owns NB=2 batch elements.
// Thread r owns gate-row r (0..255, order i,f,g,o) of w_hh1, w_ih2, w_hh2
// as fp32 in REGISTERS (loaded once, reused T=1024 times).
// h broadcast via v_readlane; gate regroup via stride-5-padded LDS.

namespace {
constexpr int Bb = 1024;
constexpr int Tt = 1024;
constexpr int Hh = 64;
constexpr int G4 = 256;   // 4*H gate rows
constexpr int NB = 2;     // batch elems per block

__device__ __forceinline__ float bcast(float v, int l) {
    return __int_as_float(__builtin_amdgcn_readlane(__float_as_int(v), l));
}
__device__ __forceinline__ float sigm(float x) {
    float e = __builtin_amdgcn_exp2f(-1.4426950408889634f * x);
    return __builtin_amdgcn_rcpf(1.0f + e);
}
__device__ __forceinline__ float tanh_f(float x) {
    float e = __builtin_amdgcn_exp2f(-2.8853900817779268f * x);
    return __builtin_amdgcn_rcpf(1.0f + e) * 2.0f - 1.0f;
}

// Dtype sniff: if the buffer holds bf16, elements at EVEN bf16 indices are
// genuine values (~N(0,0.125)) -> bf16 exponent in a sane range ~always.
// If it holds fp32, even bf16 indices are fp32 LOW half-words -> exponent
// field = random mantissa bits -> sane only ~9% of the time.
__device__ __forceinline__ bool detect_f32(const void* w) {
    const unsigned short* p = (const unsigned short*)w;
    int sane = 0;
    for (int i = 0; i < 64; ++i) {
        int e = (p[2 * i] >> 7) & 0xFF;        // bf16 exponent field
        if (e >= 107 && e <= 129) ++sane;      // |v| in ~[2^-20, 4]
    }
    return sane < 32;
}

__device__ __forceinline__ float ld(const void* p, int i, bool f32) {
    return f32 ? ((const float*)p)[i]
               : __bfloat162float(((const __hip_bfloat16*)p)[i]);
}
__device__ __forceinline__ void st(void* p, int i, float v, bool f32) {
    if (f32) ((float*)p)[i] = v;
    else     ((__hip_bfloat16*)p)[i] = __float2bfloat16(v);
}
} // namespace

__global__ __launch_bounds__(256, 2) void lstm2_kernel(
    const void* __restrict__ x,      // [B, T]
    const void* __restrict__ w_ih1,  // [256, 1]
    const void* __restrict__ w_hh1,  // [256, 64]
    const void* __restrict__ b_ih1,  // [256]
    const void* __restrict__ b_hh1,  // [256]
    const void* __restrict__ w_ih2,  // [256, 64]
    const void* __restrict__ w_hh2,  // [256, 64]
    const void* __restrict__ b_ih2,  // [256]
    const void* __restrict__ b_hh2,  // [256]
    const void* __restrict__ w_lin,  // [1, 64]
    const void* __restrict__ b_lin,  // [1]
    void* __restrict__ out)          // [B, T]
{
    const int r    = threadIdx.x;  // gate row
    const int lane = r & 63;
    const int wv   = r >> 6;
    const int bbase = blockIdx.x * NB;

    const bool f32 = detect_f32(w_hh1);   // uniform across grid

    __shared__ float h1s[NB][Hh];
    __shared__ float h2s[NB][Hh];
    __shared__ float gl[G4 * 5];   // gate preacts, stride-5 pad (conflict-free)

    // ---- one-time: weights for row r into registers (fp32) ----
    float wh1[Hh], wi2[Hh], wh2[Hh];
#pragma unroll
    for (int k = 0; k < Hh; ++k) {
        wh1[k] = ld(w_hh1, r * Hh + k, f32);
        wi2[k] = ld(w_ih2, r * Hh + k, f32);
        wh2[k] = ld(w_hh2, r * Hh + k, f32);
    }
    const float wih1_r = ld(w_ih1, r, f32);
    const float bias1  = ld(b_ih1, r, f32) + ld(b_hh1, r, f32);
    const float bias2  = ld(b_ih2, r, f32) + ld(b_hh2, r, f32);
    const float wlin_u = ld(w_lin, lane, f32);
    const float blin   = ld(b_lin, 0, f32);

    for (int i = r; i < NB * Hh; i += 256) {
        (&h1s[0][0])[i] = 0.0f;
        (&h2s[0][0])[i] = 0.0f;
    }
    float c1 = 0.0f, c2 = 0.0f;   // state for (b=wv, u=lane), valid when wv < NB
    __syncthreads();

    float xc[NB], xn[NB];
#pragma unroll
    for (int b = 0; b < NB; ++b) xc[b] = ld(x, (bbase + b) * Tt, f32);

    for (int t = 0; t < Tt; ++t) {
        const int tn = (t + 1 < Tt) ? (t + 1) : t;
#pragma unroll
        for (int b = 0; b < NB; ++b) xn[b] = ld(x, (bbase + b) * Tt + tn, f32);

        // ---- layer-1 gate preactivations ----
        float vh[NB], acc[NB];
#pragma unroll
        for (int b = 0; b < NB; ++b) vh[b] = h1s[b][lane];
#pragma unroll
        for (int b = 0; b < NB; ++b) acc[b] = fmaf(xc[b], wih1_r, bias1);
#pragma unroll
        for (int k = 0; k < Hh; ++k) {
#pragma unroll
            for (int b = 0; b < NB; ++b)
                acc[b] = fmaf(bcast(vh[b], k), wh1[k], acc[b]);
        }
#pragma unroll
        for (int b = 0; b < NB; ++b) gl[r * 5 + b] = acc[b];
        __syncthreads();

        // ---- layer-1 cell update: thread (b=wv, u=lane) ----
        if (wv < NB) {
            const int b = wv, u = lane;
            float ai = gl[u * 5 + b];
            float af = gl[(u + 64) * 5 + b];
            float ag = gl[(u + 128) * 5 + b];
            float ao = gl[(u + 192) * 5 + b];
            float ig = sigm(ai), fg = sigm(af), gg = tanh_f(ag), og = sigm(ao);
            c1 = fmaf(fg, c1, ig * gg);
            h1s[b][u] = og * tanh_f(c1);
        }
        __syncthreads();

        // ---- layer-2 gate preactivations ----
        float va[NB], vb[NB];
#pragma unroll
        for (int b = 0; b < NB; ++b) { va[b] = h1s[b][lane]; vb[b] = h2s[b][lane]; }
#pragma unroll
        for (int b = 0; b < NB; ++b) acc[b] = bias2;
#pragma unroll
        for (int k = 0; k < Hh; ++k) {
#pragma unroll
            for (int b = 0; b < NB; ++b)
                acc[b] = fmaf(bcast(va[b], k), wi2[k], acc[b]);
        }
#pragma unroll
        for (int k = 0; k < Hh; ++k) {
#pragma unroll
            for (int b = 0; b < NB; ++b)
                acc[b] = fmaf(bcast(vb[b], k), wh2[k], acc[b]);
        }
#pragma unroll
        for (int b = 0; b < NB; ++b) gl[r * 5 + b] = acc[b];
        __syncthreads();

        // ---- layer-2 cell update + linear head + store ----
        if (wv < NB) {
            const int b = wv, u = lane;
            float ai = gl[u * 5 + b];
            float af = gl[(u + 64) * 5 + b];
            float ag = gl[(u + 128) * 5 + b];
            float ao = gl[(u + 192) * 5 + b];
            float ig = sigm(ai), fg = sigm(af), gg = tanh_f(ag), og = sigm(ao);
            c2 = fmaf(fg, c2, ig * gg);
            float h = og * tanh_f(c2);
            h2s[b][u] = h;
            float p = h * wlin_u;
#pragma unroll
            for (int off = 32; off > 0; off >>= 1) p += __shfl_xor(p, off, 64);
            if (u == 0) st(out, (bbase + b) * Tt + t, p + blin, f32);
        }
        __syncthreads();

#pragma unroll
        for (int b = 0; b < NB; ++b) xc[b] = xn[b];
    }
}

extern "C" void kernel_launch(void* const* d_in, const int* in_sizes, int n_in,
                              void* d_out, int out_size, void* d_ws, size_t ws_size,
                              hipStream_t stream)
{
    (void)in_sizes; (void)n_in; (void)out_size; (void)d_ws; (void)ws_size;
    lstm2_kernel<<<dim3(Bb / NB), dim3(256), 0, stream>>>(
        d_in[0],   // x
        d_in[1],   // w_ih1
        d_in[2],   // w_hh1
        d_in[3],   // b_ih1
        d_in[4],   // b_hh1
        d_in[5],   // w_ih2
        d_in[6],   // w_hh2
        d_in[7],   // b_ih2
        d_in[8],   // b_hh2
        d_in[9],   // w_lin
        d_in[10],  // b_lin
        d_out);
}

// Round 3
// 2449.129 us; speedup vs baseline: 11.1885x; 11.1885x over previous
//
#include <hip/hip_runtime.h>
#include <hip/hip_bf16.h>

// LSTM2: B=1024, T=1024, H=64, 2-layer LSTM + linear head, fp32 state.
// R3: fix scratch spill (42.5 GB HBM fetch in R2) by packing weights as fp16
// pairs (96 VGPRs total) with dtype branch hoisted OUT of the unrolled init
// loops, and use v_dot2_f32_f16 (2 MAC/instr, fp32 accum) with readlane
// broadcast of fp16-packed h.
//
// Mapping: 512 blocks x 256 threads, NB=2 batches/block. Thread r owns gate
// row r (order i,f,g,o) of w_hh1/w_ih2/w_hh2 as 32 packed-fp16-pair VGPRs per
// matrix. h is re-packed to fp16 pairs in LDS each layer (sub-word writes),
// broadcast with one readlane per 2 MACs. 4 barriers/timestep.

typedef _Float16 h2_t __attribute__((ext_vector_type(2)));

namespace {
constexpr int Bb = 1024;
constexpr int Tt = 1024;
constexpr int Hh = 64;
constexpr int NB = 2;

__device__ __forceinline__ float sigm(float x) {
    float e = __builtin_amdgcn_exp2f(-1.4426950408889634f * x);
    return __builtin_amdgcn_rcpf(1.0f + e);
}
__device__ __forceinline__ float tanh_f(float x) {
    float e = __builtin_amdgcn_exp2f(-2.8853900817779268f * x);
    return __builtin_amdgcn_rcpf(1.0f + e) * 2.0f - 1.0f;
}

// Dtype sniff (worked in R2): fp32 buffers read at even bf16 indices give
// random exponent fields; genuine bf16 weights ~N(0,0.125) are ~always sane.
__device__ __forceinline__ bool detect_f32(const void* w) {
    const unsigned short* p = (const unsigned short*)w;
    int sane = 0;
    for (int i = 0; i < 64; ++i) {
        int e = (p[2 * i] >> 7) & 0xFF;
        if (e >= 107 && e <= 129) ++sane;
    }
    return sane < 32;
}
__device__ __forceinline__ float ld(const void* p, int i, bool f32) {
    return f32 ? ((const float*)p)[i]
               : __bfloat162float(((const __hip_bfloat16*)p)[i]);
}
__device__ __forceinline__ void st(void* p, int i, float v, bool f32) {
    if (f32) ((float*)p)[i] = v;
    else     ((__hip_bfloat16*)p)[i] = __float2bfloat16(v);
}
__device__ __forceinline__ h2_t u2h(unsigned int u) {
    h2_t h; __builtin_memcpy(&h, &u, 4); return h;
}
__device__ __forceinline__ unsigned int rl(unsigned int v, int l) {
    return (unsigned int)__builtin_amdgcn_readlane((int)v, l);
}
} // namespace

__global__ __launch_bounds__(256, 2) void lstm2_kernel(
    const void* __restrict__ x,      // [B, T]
    const void* __restrict__ w_ih1,  // [256, 1]
    const void* __restrict__ w_hh1,  // [256, 64]
    const void* __restrict__ b_ih1,  // [256]
    const void* __restrict__ b_hh1,  // [256]
    const void* __restrict__ w_ih2,  // [256, 64]
    const void* __restrict__ w_hh2,  // [256, 64]
    const void* __restrict__ b_ih2,  // [256]
    const void* __restrict__ b_hh2,  // [256]
    const void* __restrict__ w_lin,  // [1, 64]
    const void* __restrict__ b_lin,  // [1]
    void* __restrict__ out)          // [B, T]
{
    const int r    = threadIdx.x;   // gate row 0..255
    const int lane = r & 63;
    const int wv   = r >> 6;
    const int bbase = blockIdx.x * NB;

    const bool f32 = detect_f32(w_hh1);

    __shared__ float gl[256 * 6];          // gate preacts, stride 6 (b64-aligned)
    __shared__ unsigned int h1p[NB][32];   // h1 as packed fp16 pairs
    __shared__ unsigned int h2p[NB][32];   // h2 as packed fp16 pairs

    // ---- one-time: row r of the 3 matrices -> 96 packed-fp16 VGPRs ----
    h2_t wh1[32], wi2[32], wh2[32];
    if (f32) {
        const float* W1 = (const float*)w_hh1 + r * Hh;
        const float* W2 = (const float*)w_ih2 + r * Hh;
        const float* W3 = (const float*)w_hh2 + r * Hh;
#pragma unroll
        for (int j = 0; j < 32; ++j) {
            wh1[j] = h2_t{(_Float16)W1[2*j], (_Float16)W1[2*j+1]};
            wi2[j] = h2_t{(_Float16)W2[2*j], (_Float16)W2[2*j+1]};
            wh2[j] = h2_t{(_Float16)W3[2*j], (_Float16)W3[2*j+1]};
        }
    } else {
        const __hip_bfloat16* W1 = (const __hip_bfloat16*)w_hh1 + r * Hh;
        const __hip_bfloat16* W2 = (const __hip_bfloat16*)w_ih2 + r * Hh;
        const __hip_bfloat16* W3 = (const __hip_bfloat16*)w_hh2 + r * Hh;
#pragma unroll
        for (int j = 0; j < 32; ++j) {
            wh1[j] = h2_t{(_Float16)__bfloat162float(W1[2*j]),
                          (_Float16)__bfloat162float(W1[2*j+1])};
            wi2[j] = h2_t{(_Float16)__bfloat162float(W2[2*j]),
                          (_Float16)__bfloat162float(W2[2*j+1])};
            wh2[j] = h2_t{(_Float16)__bfloat162float(W3[2*j]),
                          (_Float16)__bfloat162float(W3[2*j+1])};
        }
    }
    const float wih1_r = ld(w_ih1, r, f32);
    const float bias1  = ld(b_ih1, r, f32) + ld(b_hh1, r, f32);
    const float bias2  = ld(b_ih2, r, f32) + ld(b_hh2, r, f32);
    const float wlin_u = ld(w_lin, lane, f32);
    const float blin   = ld(b_lin, 0, f32);

    if (r < NB * 32) { ((unsigned int*)h1p)[r] = 0u; ((unsigned int*)h2p)[r] = 0u; }
    float c1 = 0.0f, c2 = 0.0f;   // state for (b=wv, u=lane), valid when wv < NB
    __syncthreads();

    float xc0 = ld(x, (bbase + 0) * Tt, f32);
    float xc1 = ld(x, (bbase + 1) * Tt, f32);

    for (int t = 0; t < Tt; ++t) {
        const int tn = (t + 1 < Tt) ? (t + 1) : t;
        const float xn0 = ld(x, (bbase + 0) * Tt + tn, f32);
        const float xn1 = ld(x, (bbase + 1) * Tt + tn, f32);

        // ---- layer-1 gate preacts: acc += W_hh1[r,:] . h1 (fp16 dot2) ----
        unsigned int v10 = h1p[0][lane & 31];
        unsigned int v11 = h1p[1][lane & 31];
        float acc0 = fmaf(xc0, wih1_r, bias1);
        float acc1 = fmaf(xc1, wih1_r, bias1);
#pragma unroll
        for (int j = 0; j < 32; ++j) {
            acc0 = __builtin_amdgcn_fdot2(wh1[j], u2h(rl(v10, j)), acc0, false);
            acc1 = __builtin_amdgcn_fdot2(wh1[j], u2h(rl(v11, j)), acc1, false);
        }
        *(float2*)&gl[r * 6] = make_float2(acc0, acc1);
        __syncthreads();

        // ---- layer-1 cell update: thread (b=wv, u=lane) ----
        if (wv < NB) {
            const int b = wv, u = lane;
            float ai = gl[u * 6 + b];
            float af = gl[(u + 64) * 6 + b];
            float ag = gl[(u + 128) * 6 + b];
            float ao = gl[(u + 192) * 6 + b];
            float ig = sigm(ai), fg = sigm(af), gg = tanh_f(ag), og = sigm(ao);
            c1 = fmaf(fg, c1, ig * gg);
            ((_Float16*)h1p[b])[u] = (_Float16)(og * tanh_f(c1));
        }
        __syncthreads();

        // ---- layer-2 gate preacts: acc = b2 + W_ih2.h1new + W_hh2.h2 ----
        unsigned int a0 = h1p[0][lane & 31];
        unsigned int a1 = h1p[1][lane & 31];
        unsigned int b0 = h2p[0][lane & 31];
        unsigned int b1 = h2p[1][lane & 31];
        acc0 = bias2;
        acc1 = bias2;
#pragma unroll
        for (int j = 0; j < 32; ++j) {
            acc0 = __builtin_amdgcn_fdot2(wi2[j], u2h(rl(a0, j)), acc0, false);
            acc1 = __builtin_amdgcn_fdot2(wi2[j], u2h(rl(a1, j)), acc1, false);
            acc0 = __builtin_amdgcn_fdot2(wh2[j], u2h(rl(b0, j)), acc0, false);
            acc1 = __builtin_amdgcn_fdot2(wh2[j], u2h(rl(b1, j)), acc1, false);
        }
        *(float2*)&gl[r * 6] = make_float2(acc0, acc1);
        __syncthreads();

        // ---- layer-2 cell update + linear head ----
        if (wv < NB) {
            const int b = wv, u = lane;
            float ai = gl[u * 6 + b];
            float af = gl[(u + 64) * 6 + b];
            float ag = gl[(u + 128) * 6 + b];
            float ao = gl[(u + 192) * 6 + b];
            float ig = sigm(ai), fg = sigm(af), gg = tanh_f(ag), og = sigm(ao);
            c2 = fmaf(fg, c2, ig * gg);
            float h = og * tanh_f(c2);
            ((_Float16*)h2p[b])[u] = (_Float16)h;
            float p = h * wlin_u;
#pragma unroll
            for (int off = 32; off > 0; off >>= 1) p += __shfl_xor(p, off, 64);
            if (u == 0) st(out, (bbase + b) * Tt + t, p + blin, f32);
        }
        __syncthreads();

        xc0 = xn0;
        xc1 = xn1;
    }
}

extern "C" void kernel_launch(void* const* d_in, const int* in_sizes, int n_in,
                              void* d_out, int out_size, void* d_ws, size_t ws_size,
                              hipStream_t stream)
{
    (void)in_sizes; (void)n_in; (void)out_size; (void)d_ws; (void)ws_size;
    lstm2_kernel<<<dim3(Bb / NB), dim3(256), 0, stream>>>(
        d_in[0], d_in[1], d_in[2], d_in[3], d_in[4], d_in[5],
        d_in[6], d_in[7], d_in[8], d_in[9], d_in[10], d_out);
}

// Round 4
// 1578.266 us; speedup vs baseline: 17.3621x; 1.5518x over previous
//
#include <hip/hip_runtime.h>
#include <hip/hip_bf16.h>

// LSTM2: B=1024, T=1024, H=64. R4: readlane-free fdot2 design.
// 1024 blocks (1 batch each) x 128 threads (2 waves).
//   wave0 lane u: gate rows u (i), u+64 (f)
//   wave1 lane u: gate rows u+128 (g), u+192 (o)
// Weights: 2 rows x 3 matrices as packed fp16 pairs = 192 VGPRs/thread,
// loaded once (dtype branch hoisted OUT of unrolled loops - R2 spill lesson).
// h lives in LDS as fp16[64]; broadcast via all-lanes-same-address
// ds_read_b128 (conflict-free, LDS pipe co-issues with VALU). 3 barriers/step.
// Gate exchange: wave1 -> (g,o) -> wave0 does cell1; wave0 -> (i,f) -> wave1
// does cell2 + linear head. x staged to LDS once; no global loads in loop.

typedef _Float16 h2v __attribute__((ext_vector_type(2)));
typedef unsigned int u32;

namespace {
constexpr int Bb = 1024;
constexpr int Tt = 1024;
constexpr int Hh = 64;

__device__ __forceinline__ float sigm(float x) {
    float e = __builtin_amdgcn_exp2f(-1.4426950408889634f * x);
    return __builtin_amdgcn_rcpf(1.0f + e);
}
__device__ __forceinline__ float tanh_f(float x) {
    float e = __builtin_amdgcn_exp2f(-2.8853900817779268f * x);
    return __builtin_amdgcn_rcpf(1.0f + e) * 2.0f - 1.0f;
}
// Dtype sniff (proven R2/R3): fp32 data read at even bf16 indices has random
// exponent fields; genuine bf16 weights ~N(0,0.125) are ~always in-range.
__device__ __forceinline__ bool detect_f32(const void* w) {
    const unsigned short* p = (const unsigned short*)w;
    int sane = 0;
    for (int i = 0; i < 64; ++i) {
        int e = (p[2 * i] >> 7) & 0xFF;
        if (e >= 107 && e <= 129) ++sane;
    }
    return sane < 32;
}
__device__ __forceinline__ float ld(const void* p, int i, bool f32) {
    return f32 ? ((const float*)p)[i]
               : __bfloat162float(((const __hip_bfloat16*)p)[i]);
}
__device__ __forceinline__ void st(void* p, int i, float v, bool f32) {
    if (f32) ((float*)p)[i] = v;
    else     ((__hip_bfloat16*)p)[i] = __float2bfloat16(v);
}
__device__ __forceinline__ h2v uph(u32 v) {
    h2v r; __builtin_memcpy(&r, &v, 4); return r;
}
__device__ __forceinline__ float fd(h2v w, u32 h, float acc) {
    return __builtin_amdgcn_fdot2(w, uph(h), acc, false);
}
} // namespace

__global__ __launch_bounds__(128, 2) void lstm2_kernel(
    const void* __restrict__ x,      // [B, T]
    const void* __restrict__ w_ih1,  // [256, 1]
    const void* __restrict__ w_hh1,  // [256, 64]
    const void* __restrict__ b_ih1,  // [256]
    const void* __restrict__ b_hh1,  // [256]
    const void* __restrict__ w_ih2,  // [256, 64]
    const void* __restrict__ w_hh2,  // [256, 64]
    const void* __restrict__ b_ih2,  // [256]
    const void* __restrict__ b_hh2,  // [256]
    const void* __restrict__ w_lin,  // [1, 64]
    const void* __restrict__ b_lin,  // [1]
    void* __restrict__ out)          // [B, T]
{
    const int u  = threadIdx.x & 63;   // lane = hidden unit
    const int w  = threadIdx.x >> 6;   // wave 0: (i,f), wave 1: (g,o)
    const int ra = u + 128 * w;        // first owned gate row
    const int rb = u + 64 + 128 * w;   // second owned gate row
    const int b  = blockIdx.x;         // batch element

    const bool f32 = detect_f32(w_hh1);

    __shared__ __align__(16) float     xs[Tt];     // staged x row (fp32)
    __shared__ __align__(16) _Float16  h1b[Hh];    // h1, fp16 (pair-readable)
    __shared__ __align__(16) _Float16  h2b[Hh];    // h2, fp16
    __shared__ float2 go1[Hh];   // wave1 -> wave0: (g,o) preacts L1
    __shared__ float2 if2[Hh];   // wave0 -> wave1: (i,f) preacts L2

    // ---- stage x row into LDS (one-time) ----
    for (int i = threadIdx.x; i < Tt; i += 128) xs[i] = ld(x, b * Tt + i, f32);

    // ---- one-time: rows ra, rb of the 3 matrices -> 192 packed-fp16 VGPRs --
    h2v w1a[32], w1b[32], w2a[32], w2b[32], w3a[32], w3b[32];
    if (f32) {
        const float* A = (const float*)w_hh1;
        const float* Bm = (const float*)w_ih2;
        const float* C = (const float*)w_hh2;
#pragma unroll
        for (int j = 0; j < 32; ++j) {
            w1a[j] = h2v{(_Float16)A[ra*64+2*j], (_Float16)A[ra*64+2*j+1]};
            w1b[j] = h2v{(_Float16)A[rb*64+2*j], (_Float16)A[rb*64+2*j+1]};
            w2a[j] = h2v{(_Float16)Bm[ra*64+2*j], (_Float16)Bm[ra*64+2*j+1]};
            w2b[j] = h2v{(_Float16)Bm[rb*64+2*j], (_Float16)Bm[rb*64+2*j+1]};
            w3a[j] = h2v{(_Float16)C[ra*64+2*j], (_Float16)C[ra*64+2*j+1]};
            w3b[j] = h2v{(_Float16)C[rb*64+2*j], (_Float16)C[rb*64+2*j+1]};
        }
    } else {
        const __hip_bfloat16* A = (const __hip_bfloat16*)w_hh1;
        const __hip_bfloat16* Bm = (const __hip_bfloat16*)w_ih2;
        const __hip_bfloat16* C = (const __hip_bfloat16*)w_hh2;
#pragma unroll
        for (int j = 0; j < 32; ++j) {
            w1a[j] = h2v{(_Float16)__bfloat162float(A[ra*64+2*j]),
                         (_Float16)__bfloat162float(A[ra*64+2*j+1])};
            w1b[j] = h2v{(_Float16)__bfloat162float(A[rb*64+2*j]),
                         (_Float16)__bfloat162float(A[rb*64+2*j+1])};
            w2a[j] = h2v{(_Float16)__bfloat162float(Bm[ra*64+2*j]),
                         (_Float16)__bfloat162float(Bm[ra*64+2*j+1])};
            w2b[j] = h2v{(_Float16)__bfloat162float(Bm[rb*64+2*j]),
                         (_Float16)__bfloat162float(Bm[rb*64+2*j+1])};
            w3a[j] = h2v{(_Float16)__bfloat162float(C[ra*64+2*j]),
                         (_Float16)__bfloat162float(C[ra*64+2*j+1])};
            w3b[j] = h2v{(_Float16)__bfloat162float(C[rb*64+2*j]),
                         (_Float16)__bfloat162float(C[rb*64+2*j+1])};
        }
    }
    const float wxa = ld(w_ih1, ra, f32);
    const float wxb = ld(w_ih1, rb, f32);
    const float b1a = ld(b_ih1, ra, f32) + ld(b_hh1, ra, f32);
    const float b1b = ld(b_ih1, rb, f32) + ld(b_hh1, rb, f32);
    const float b2a = ld(b_ih2, ra, f32) + ld(b_hh2, ra, f32);
    const float b2b = ld(b_ih2, rb, f32) + ld(b_hh2, rb, f32);
    const float wlin_u = ld(w_lin, u, f32);
    const float blin   = ld(b_lin, 0, f32);

    if (threadIdx.x < Hh) { h1b[u] = (_Float16)0.0f; h2b[u] = (_Float16)0.0f; }
    float c1 = 0.0f;   // valid in wave0
    float c2 = 0.0f;   // valid in wave1
    __syncthreads();

    const uint4* h1q = (const uint4*)h1b;   // 8 x uint4 = 32 fp16 pairs
    const uint4* h2q = (const uint4*)h2b;

    for (int t = 0; t < Tt; ++t) {
        const float xt = xs[t];   // broadcast read

        // ---- layer-1 gate preacts: rows ra, rb ----
        float a0 = fmaf(xt, wxa, b1a);
        float a1 = fmaf(xt, wxb, b1b);
#pragma unroll
        for (int half = 0; half < 2; ++half) {
            uint4 hq[4];
#pragma unroll
            for (int j = 0; j < 4; ++j) hq[j] = h1q[half * 4 + j];
#pragma unroll
            for (int j = 0; j < 4; ++j) {
                const int p = half * 16 + j * 4;
                a0 = fd(w1a[p+0], hq[j].x, a0); a1 = fd(w1b[p+0], hq[j].x, a1);
                a0 = fd(w1a[p+1], hq[j].y, a0); a1 = fd(w1b[p+1], hq[j].y, a1);
                a0 = fd(w1a[p+2], hq[j].z, a0); a1 = fd(w1b[p+2], hq[j].z, a1);
                a0 = fd(w1a[p+3], hq[j].w, a0); a1 = fd(w1b[p+3], hq[j].w, a1);
            }
        }
        if (w == 1) go1[u] = make_float2(a0, a1);   // (g,o)
        __syncthreads();                             // B1

        // ---- cell 1 (wave0): own (i,f) in regs, (g,o) from LDS ----
        if (w == 0) {
            float2 go = go1[u];
            float ig = sigm(a0), fg = sigm(a1);
            float gg = tanh_f(go.x), og = sigm(go.y);
            c1 = fmaf(fg, c1, ig * gg);
            h1b[u] = (_Float16)(og * tanh_f(c1));
        }
        __syncthreads();                             // B2

        // ---- layer-2 gate preacts: b2 + Wih2.h1new + Whh2.h2old ----
        a0 = b2a;
        a1 = b2b;
#pragma unroll
        for (int half = 0; half < 2; ++half) {       // phase A: h1new
            uint4 hq[4];
#pragma unroll
            for (int j = 0; j < 4; ++j) hq[j] = h1q[half * 4 + j];
#pragma unroll
            for (int j = 0; j < 4; ++j) {
                const int p = half * 16 + j * 4;
                a0 = fd(w2a[p+0], hq[j].x, a0); a1 = fd(w2b[p+0], hq[j].x, a1);
                a0 = fd(w2a[p+1], hq[j].y, a0); a1 = fd(w2b[p+1], hq[j].y, a1);
                a0 = fd(w2a[p+2], hq[j].z, a0); a1 = fd(w2b[p+2], hq[j].z, a1);
                a0 = fd(w2a[p+3], hq[j].w, a0); a1 = fd(w2b[p+3], hq[j].w, a1);
            }
        }
#pragma unroll
        for (int half = 0; half < 2; ++half) {       // phase B: h2old
            uint4 hq[4];
#pragma unroll
            for (int j = 0; j < 4; ++j) hq[j] = h2q[half * 4 + j];
#pragma unroll
            for (int j = 0; j < 4; ++j) {
                const int p = half * 16 + j * 4;
                a0 = fd(w3a[p+0], hq[j].x, a0); a1 = fd(w3b[p+0], hq[j].x, a1);
                a0 = fd(w3a[p+1], hq[j].y, a0); a1 = fd(w3b[p+1], hq[j].y, a1);
                a0 = fd(w3a[p+2], hq[j].z, a0); a1 = fd(w3b[p+2], hq[j].z, a1);
                a0 = fd(w3a[p+3], hq[j].w, a0); a1 = fd(w3b[p+3], hq[j].w, a1);
            }
        }
        if (w == 0) if2[u] = make_float2(a0, a1);    // (i,f)
        __syncthreads();                             // B3

        // ---- cell 2 + head (wave1): own (g,o) in regs, (i,f) from LDS ----
        if (w == 1) {
            float2 iff = if2[u];
            float ig = sigm(iff.x), fg = sigm(iff.y);
            float gg = tanh_f(a0), og = sigm(a1);
            c2 = fmaf(fg, c2, ig * gg);
            float h = og * tanh_f(c2);
            h2b[u] = (_Float16)h;
            float p = h * wlin_u;
#pragma unroll
            for (int off = 32; off > 0; off >>= 1) p += __shfl_xor(p, off, 64);
            if (u == 0) st(out, b * Tt + t, p + blin, f32);
        }
        // no 4th barrier needed: every cross-wave buffer re-use is separated
        // by >=1 of B1/B2/B3 in the next iteration (audited per-buffer).
    }
}

extern "C" void kernel_launch(void* const* d_in, const int* in_sizes, int n_in,
                              void* d_out, int out_size, void* d_ws, size_t ws_size,
                              hipStream_t stream)
{
    (void)in_sizes; (void)n_in; (void)out_size; (void)d_ws; (void)ws_size;
    lstm2_kernel<<<dim3(Bb), dim3(128), 0, stream>>>(
        d_in[0], d_in[1], d_in[2], d_in[3], d_in[4], d_in[5],
        d_in[6], d_in[7], d_in[8], d_in[9], d_in[10], d_out);
}

// Round 5
// 1109.808 us; speedup vs baseline: 24.6908x; 1.4221x over previous
//
#include <hip/hip_runtime.h>
#include <hip/hip_bf16.h>

// LSTM2: B=1024, T=1024, H=64. R5: MFMA formulation.
// 64 blocks (16 batches each) x 4 waves.
// D[gate_row, batch] = W[gate_row, k] . h[k, batch] via mfma_f32_16x16x32_f16:
//   M = gate rows (16/tile), N = batches (16), K = hidden (32/step).
// Wave w owns gate tiles {w, 4+w, 8+w, 12+w} = gates i,f,g,o for units
// 16w..16w+15 -> C-layouts line up -> cell update is lane-local, all lanes hot.
// Weights: 24 A-frags (96 VGPRs) register-resident, loaded once.
// h crosses LDS once per layer-step in B-layout [batch][unit] (stride 72 f16);
// L1 of step t+1 reuses the B-frags read for L2 of step t (same h1_t) -> only
// 2 barriers/step. Layout refs (learn_hip m89/m91/m120):
//   A: A[m=lane&15][k=(lane>>4)*8+j]   B: B[k=(lane>>4)*8+j][n=lane&15]
//   C/D: row=(lane>>4)*4+reg, col=lane&15

typedef _Float16 f16x8 __attribute__((ext_vector_type(8)));
typedef _Float16 f16x4 __attribute__((ext_vector_type(4)));
typedef float    f32x4 __attribute__((ext_vector_type(4)));

namespace {
constexpr int Bb = 1024;
constexpr int Tt = 1024;
constexpr int HSTR = 72;   // f16 stride per batch row of h (pad: 2-way max)
constexpr int XSTR = 1025; // f32 stride per batch row of x (conflict-free)

__device__ __forceinline__ float sigm(float x) {
    float e = __builtin_amdgcn_exp2f(-1.4426950408889634f * x);
    return __builtin_amdgcn_rcpf(1.0f + e);
}
__device__ __forceinline__ float tanh_f(float x) {
    float e = __builtin_amdgcn_exp2f(-2.8853900817779268f * x);
    return __builtin_amdgcn_rcpf(1.0f + e) * 2.0f - 1.0f;
}
// Dtype sniff (proven R2-R4): fp32 data at even bf16 indices has random
// exponent fields; genuine bf16 weights ~N(0,0.125) are ~always in-range.
__device__ __forceinline__ bool detect_f32(const void* w) {
    const unsigned short* p = (const unsigned short*)w;
    int sane = 0;
    for (int i = 0; i < 64; ++i) {
        int e = (p[2 * i] >> 7) & 0xFF;
        if (e >= 107 && e <= 129) ++sane;
    }
    return sane < 32;
}
__device__ __forceinline__ float ld(const void* p, int i, bool f32) {
    return f32 ? ((const float*)p)[i]
               : __bfloat162float(((const __hip_bfloat16*)p)[i]);
}
__device__ __forceinline__ void st(void* p, int i, float v, bool f32) {
    if (f32) ((float*)p)[i] = v;
    else     ((__hip_bfloat16*)p)[i] = __float2bfloat16(v);
}
} // namespace

__global__ __launch_bounds__(256, 1) void lstm2_kernel(
    const void* __restrict__ x,      // [B, T]
    const void* __restrict__ w_ih1,  // [256, 1]
    const void* __restrict__ w_hh1,  // [256, 64]
    const void* __restrict__ b_ih1,  // [256]
    const void* __restrict__ b_hh1,  // [256]
    const void* __restrict__ w_ih2,  // [256, 64]
    const void* __restrict__ w_hh2,  // [256, 64]
    const void* __restrict__ b_ih2,  // [256]
    const void* __restrict__ b_hh2,  // [256]
    const void* __restrict__ w_lin,  // [1, 64]
    const void* __restrict__ b_lin,  // [1]
    void* __restrict__ out)          // [B, T]
{
    const int tid  = threadIdx.x;
    const int lane = tid & 63;
    const int w    = tid >> 6;       // wave 0..3 -> unit group 16w..16w+15
    const int m    = lane & 15;      // A-row within tile / B-col (batch) / D-col
    const int quad = lane >> 4;
    const int bb   = blockIdx.x * 16;

    const bool f32 = detect_f32(w_hh1);

    __shared__ float    xs[16 * XSTR];      // staged x, fp32
    __shared__ _Float16 h1l[16 * HSTR];     // h1 in B-layout [batch][unit]
    __shared__ _Float16 h2l[16 * HSTR];     // h2 in B-layout
    __shared__ float    headp[64];          // per-wave head partials [w][batch]

    // ---- stage x (one-time, coalesced) + zero h buffers ----
    for (int i = tid; i < 16 * 1024; i += 256)
        xs[(i >> 10) * XSTR + (i & 1023)] = ld(x, (bb + (i >> 10)) * Tt + (i & 1023), f32);
    for (int i = tid; i < 16 * HSTR; i += 256) { h1l[i] = (_Float16)0; h2l[i] = (_Float16)0; }

    // ---- one-time: A-fragments of W_hh1 / W_ih2 / W_hh2 (96 VGPRs) ----
    // frag element j: W[64*q + 16*w + m][32*s + quad*8 + j]
    f16x8 wf1[4][2], wf2[4][2], wf3[4][2];
    if (f32) {
        const float* W1 = (const float*)w_hh1;
        const float* W2 = (const float*)w_ih2;
        const float* W3 = (const float*)w_hh2;
#pragma unroll
        for (int q = 0; q < 4; ++q) {
            const int row = 64 * q + 16 * w + m;
#pragma unroll
            for (int s = 0; s < 2; ++s) {
                const int base = row * 64 + 32 * s + quad * 8;
#pragma unroll
                for (int j = 0; j < 8; ++j) {
                    wf1[q][s][j] = (_Float16)W1[base + j];
                    wf2[q][s][j] = (_Float16)W2[base + j];
                    wf3[q][s][j] = (_Float16)W3[base + j];
                }
            }
        }
    } else {
        const __hip_bfloat16* W1 = (const __hip_bfloat16*)w_hh1;
        const __hip_bfloat16* W2 = (const __hip_bfloat16*)w_ih2;
        const __hip_bfloat16* W3 = (const __hip_bfloat16*)w_hh2;
#pragma unroll
        for (int q = 0; q < 4; ++q) {
            const int row = 64 * q + 16 * w + m;
#pragma unroll
            for (int s = 0; s < 2; ++s) {
                const int base = row * 64 + 32 * s + quad * 8;
#pragma unroll
                for (int j = 0; j < 8; ++j) {
                    wf1[q][s][j] = (_Float16)__bfloat162float(W1[base + j]);
                    wf2[q][s][j] = (_Float16)__bfloat162float(W2[base + j]);
                    wf3[q][s][j] = (_Float16)__bfloat162float(W3[base + j]);
                }
            }
        }
    }
    // ---- per-(tile,reg) scalars: D-layout rows = 64*q + 16*w + quad*4 + r ----
    float b1v[4][4], b2v[4][4], wxv[4][4], wl[4];
#pragma unroll
    for (int q = 0; q < 4; ++q)
#pragma unroll
        for (int r = 0; r < 4; ++r) {
            const int row = 64 * q + 16 * w + quad * 4 + r;
            b1v[q][r] = ld(b_ih1, row, f32) + ld(b_hh1, row, f32);
            b2v[q][r] = ld(b_ih2, row, f32) + ld(b_hh2, row, f32);
            wxv[q][r] = ld(w_ih1, row, f32);
        }
#pragma unroll
    for (int r = 0; r < 4; ++r) wl[r] = ld(w_lin, 16 * w + quad * 4 + r, f32);
    const float blin = ld(b_lin, 0, f32);

    f16x8 bh1[2] = {};            // h1 B-frags (state h1_{t-1}; zero at t=0)
    f32x4 c1 = {0,0,0,0}, c2 = {0,0,0,0};
    __syncthreads();

    const int xrow = m * XSTR;
    float xt = xs[xrow];

    for (int t = 0; t < Tt; ++t) {
        // prefetch: h2_{t-1} B-frags (safe: written pre-B3 of t-1) + next x
        f16x8 bh2[2];
        bh2[0] = *(const f16x8*)(h2l + m * HSTR + 0  + quad * 8);
        bh2[1] = *(const f16x8*)(h2l + m * HSTR + 32 + quad * 8);
        const float xtn = xs[xrow + ((t + 1 < Tt) ? t + 1 : t)];

        // ---- layer 1: gates = W1.h1_{t-1} + x*wx + b1 ----
        f32x4 a1[4];
#pragma unroll
        for (int q = 0; q < 4; ++q)
#pragma unroll
            for (int r = 0; r < 4; ++r) a1[q][r] = fmaf(xt, wxv[q][r], b1v[q][r]);
#pragma unroll
        for (int q = 0; q < 4; ++q) {
            a1[q] = __builtin_amdgcn_mfma_f32_16x16x32_f16(wf1[q][0], bh1[0], a1[q], 0, 0, 0);
            a1[q] = __builtin_amdgcn_mfma_f32_16x16x32_f16(wf1[q][1], bh1[1], a1[q], 0, 0, 0);
        }
        // cell 1 (lane-local: unit = 16w + quad*4 + r, batch = m)
        f16x4 h1o;
#pragma unroll
        for (int r = 0; r < 4; ++r) {
            float ig = sigm(a1[0][r]), fg = sigm(a1[1][r]);
            float gg = tanh_f(a1[2][r]), og = sigm(a1[3][r]);
            c1[r] = fmaf(fg, c1[r], ig * gg);
            h1o[r] = (_Float16)(og * tanh_f(c1[r]));
        }
        *(f16x4*)(h1l + m * HSTR + 16 * w + quad * 4) = h1o;
        __syncthreads();                                   // B1: h1_t ready

        // fresh h1_t B-frags (reused by L1 of t+1 -- same vector)
        bh1[0] = *(const f16x8*)(h1l + m * HSTR + 0  + quad * 8);
        bh1[1] = *(const f16x8*)(h1l + m * HSTR + 32 + quad * 8);

        // ---- layer 2: gates = W2.h1_t + W3.h2_{t-1} + b2 ----
        f32x4 a2[4];
#pragma unroll
        for (int q = 0; q < 4; ++q)
#pragma unroll
            for (int r = 0; r < 4; ++r) a2[q][r] = b2v[q][r];
#pragma unroll
        for (int q = 0; q < 4; ++q) {
            a2[q] = __builtin_amdgcn_mfma_f32_16x16x32_f16(wf2[q][0], bh1[0], a2[q], 0, 0, 0);
            a2[q] = __builtin_amdgcn_mfma_f32_16x16x32_f16(wf2[q][1], bh1[1], a2[q], 0, 0, 0);
            a2[q] = __builtin_amdgcn_mfma_f32_16x16x32_f16(wf3[q][0], bh2[0], a2[q], 0, 0, 0);
            a2[q] = __builtin_amdgcn_mfma_f32_16x16x32_f16(wf3[q][1], bh2[1], a2[q], 0, 0, 0);
        }
        // cell 2 + head partial
        f16x4 h2o;
        float p = 0.0f;
#pragma unroll
        for (int r = 0; r < 4; ++r) {
            float ig = sigm(a2[0][r]), fg = sigm(a2[1][r]);
            float gg = tanh_f(a2[2][r]), og = sigm(a2[3][r]);
            c2[r] = fmaf(fg, c2[r], ig * gg);
            float h = og * tanh_f(c2[r]);
            h2o[r] = (_Float16)h;
            p = fmaf(h, wl[r], p);
        }
        *(f16x4*)(h2l + m * HSTR + 16 * w + quad * 4) = h2o;
        p += __shfl_xor(p, 16);
        p += __shfl_xor(p, 32);           // sum over this wave's 16 units
        if (quad == 0) headp[w * 16 + m] = p;
        __syncthreads();                                   // B3: h2_t + partials

        if (tid < 16) {
            float s = headp[tid] + headp[16 + tid] + headp[32 + tid]
                    + headp[48 + tid] + blin;
            st(out, (bb + tid) * Tt + t, s, f32);
        }
        xt = xtn;
    }
}

extern "C" void kernel_launch(void* const* d_in, const int* in_sizes, int n_in,
                              void* d_out, int out_size, void* d_ws, size_t ws_size,
                              hipStream_t stream)
{
    (void)in_sizes; (void)n_in; (void)out_size; (void)d_ws; (void)ws_size;
    lstm2_kernel<<<dim3(Bb / 16), dim3(256), 0, stream>>>(
        d_in[0], d_in[1], d_in[2], d_in[3], d_in[4], d_in[5],
        d_in[6], d_in[7], d_in[8], d_in[9], d_in[10], d_out);
}